// Round 4
// baseline (2589.933 us; speedup 1.0000x reference)
//
#include <hip/hip_runtime.h>
#include <hip/hip_bf16.h>

#define EDIM 1024
#define MDIM 4096
#define SEQ  2048
#define NB   4
#define ROWS 8192

typedef short bh8 __attribute__((ext_vector_type(8)));
typedef float f32x16 __attribute__((ext_vector_type(16)));

__device__ __forceinline__ float bf2f(unsigned short u) {
    return __uint_as_float(((unsigned int)u) << 16);
}
__device__ __forceinline__ unsigned short f2bf(float f) {
    unsigned int u = __float_as_uint(f);
    u += 0x7FFFu + ((u >> 16) & 1u);
    return (unsigned short)(u >> 16);
}
__device__ __forceinline__ void splitf(float v, unsigned short& h, unsigned short& l) {
    h = f2bf(v);
    l = f2bf(v - __uint_as_float(((unsigned int)h) << 16));
}
__device__ __forceinline__ void ld4f(const float* __restrict__ p, float* d) {
    const float4 v = *reinterpret_cast<const float4*>(p);
    d[0] = v.x; d[1] = v.y; d[2] = v.z; d[3] = v.w;
}
__device__ __forceinline__ void ld4h(const unsigned short* __restrict__ p, float* d) {
    const ushort4 v = *reinterpret_cast<const ushort4*>(p);
    d[0] = bf2f(v.x); d[1] = bf2f(v.y); d[2] = bf2f(v.z); d[3] = bf2f(v.w);
}

// Fragment-tiled ("F-layout") index: element (n,k) of an [N][K] matrix lives at
// ((((n/32)*(K/16)+k/16)*2+(k/8)%2)*32 + n%32)*8  (+ k%8)
// A wave's 64 lanes (lane = ((k>>3)&1)*32 + n&31, elem = k&7) read one
// contiguous 1KB chunk -> exactly the MFMA A/B operand shape.
__device__ __forceinline__ long long tidx8(int n, int k, int KD16) {
    return ((((long long)(n >> 5) * KD16 + (k >> 4)) * 2 + ((k >> 3) & 1)) * 32 + (n & 31)) * 8;
}

// dtype sniffer: flag=1 -> inputs are bf16, flag=0 -> f32
__global__ __launch_bounds__(64)
void sniff_k(const unsigned int* __restrict__ w, int* __restrict__ flag) {
    int ok = 0;
    const int base = threadIdx.x * 32;
#pragma unroll
    for (int i = 0; i < 32; ++i) {
        const unsigned int v = w[base + i];
        const unsigned int lo = v & 0xFFFFu, hi = v >> 16;
        const unsigned int el = (lo >> 7) & 0xFF, eh = (hi >> 7) & 0xFF;
        const bool okl = (lo == 0u) || (el >= 0x30u && el <= 0x7Eu);
        const bool okh = (hi == 0u) || (eh >= 0x30u && eh <= 0x7Eu);
        ok += (okl && okh) ? 1 : 0;
    }
#pragma unroll
    for (int off = 32; off > 0; off >>= 1) ok += __shfl_down(ok, off);
    if (threadIdx.x == 0) *flag = (ok > 1400) ? 1 : 0;
}

// embedding gather -> h in split F-layout (KD16=64)
__global__ __launch_bounds__(256)
void gather_k(const int* __restrict__ x, const void* __restrict__ emb,
              unsigned short* __restrict__ oh, unsigned short* __restrict__ ol,
              const int* __restrict__ flagp) {
    const int bf = *flagp;
    const int row = blockIdx.x;
    const int idx = x[row];
    const int k = threadIdx.x * 4;
    const long long off = (long long)idx * EDIM + k;
    float d[4];
    if (bf) ld4h((const unsigned short*)emb + off, d);
    else    ld4f((const float*)emb + off, d);
    unsigned short h0, l0, h1, l1, h2, l2, h3, l3;
    splitf(d[0], h0, l0); splitf(d[1], h1, l1);
    splitf(d[2], h2, l2); splitf(d[3], h3, l3);
    const long long o = (((long long)(row >> 5) * 64 + (k >> 4)) * 2 + ((k >> 3) & 1)) * 256
                        + (row & 31) * 8 + (k & 7);
    *reinterpret_cast<ushort4*>(oh + o) = make_ushort4(h0, h1, h2, h3);
    *reinterpret_cast<ushort4*>(ol + o) = make_ushort4(l0, l1, l2, l3);
}

// Weights: transpose + split + fragment-tile: in [Kd,Nd] -> hi/lo tiled [Nd,Kd]
__global__ __launch_bounds__(256)
void splitT_tiled_k(const void* __restrict__ in, unsigned short* __restrict__ oh,
                    unsigned short* __restrict__ ol, int Kd, int Nd,
                    long long inOff, const int* __restrict__ flagp, int bF) {
    const int bf = bF ? *flagp : 0;
    const int k0 = blockIdx.y * 32, n0 = blockIdx.x * 32;
    const int KD16 = Kd >> 4;
    __shared__ float t[32][33];
    const int c = threadIdx.x & 31, r0 = threadIdx.x >> 5;
#pragma unroll
    for (int i = 0; i < 4; ++i) {
        const int r = r0 + i * 8;
        const long long off = inOff + (long long)(k0 + r) * Nd + n0 + c;
        t[r][c] = bf ? bf2f(((const unsigned short*)in)[off]) : ((const float*)in)[off];
    }
    __syncthreads();
#pragma unroll
    for (int i = 0; i < 4; ++i) {
        const int r = r0 + i * 8;
        const float v = t[c][r];
        unsigned short hh, ll;
        splitf(v, hh, ll);
        const int n = n0 + r, k = k0 + c;
        const long long oo = tidx8(n, k, KD16) + (k & 7);
        oh[oo] = hh; ol[oo] = ll;
    }
}

// Split-bf16 MFMA GEMM, all-register: C[M,N] = op(A[M,K] @ B^T + bias).
// A and B both pre-split hi/lo in F-layout; fragments stream global->reg
// (contiguous 1KB/wave loads), register double-buffered, NO LDS, NO barriers.
// 128x128 block, 4 waves (64x64 each, 2x2 frags of 32x32x16), 3 blocks/CU.
// OM: 0 = plain C (f32 / bf16-by-flag), 1 = F-layout hi/lo out, 3 = transposed
// F-layout out (v for PV).
template<int OM, bool BIAS, bool RELU, bool MASK>
__global__ __launch_bounds__(256, 3)
void mgemm_k(const unsigned short* __restrict__ Ah,
             const unsigned short* __restrict__ Al,
             const unsigned short* __restrict__ Bh,
             const unsigned short* __restrict__ Bl,
             const void* __restrict__ biasv,
             void* __restrict__ Cv, void* __restrict__ Cv2,
             int M, int N, int K,
             long long sA, long long sB, long long sC,
             long long biasBase, float scale, int oKD16, long long zOut, int rowMul,
             const int* __restrict__ flagp, int bF, int cF) {
    const int flag = *flagp;
    const int bfBias = bF ? flag : 0;
    const int bfC = cF ? flag : 0;

    Ah += (long long)blockIdx.z * sA;
    Al += (long long)blockIdx.z * sA;
    Bh += (long long)blockIdx.z * sB;
    Bl += (long long)blockIdx.z * sB;
    const long long zC = (long long)blockIdx.z * sC;
    const int rowOff = rowMul * blockIdx.z;

    // XCD remap: bx-minor within XCD -> A panel back-to-back, B panels L2-resident
    const int GX = gridDim.x;
    const int f = blockIdx.y * GX + blockIdx.x;
    const int gxpc = GX >> 3;
    const int xcd = f & 7, p = f >> 3;
    const int bx = xcd * gxpc + (p % gxpc);
    const int by = p / gxpc;
    const int brow = by * 128, bcol = bx * 128;

    const int tid = threadIdx.x;
    const int lane = tid & 63, wave = tid >> 6;
    const int wr = wave >> 1, wc = wave & 1;
    const int l31 = lane & 31, lhi = lane >> 5;

    if (MASK && (bcol + 127 < brow)) {
#pragma unroll
        for (int mi = 0; mi < 2; ++mi) {
            const int rbase = brow + wr * 64 + mi * 32 + 4 * lhi;
#pragma unroll
            for (int ni = 0; ni < 2; ++ni) {
                const int c = bcol + wc * 64 + ni * 32 + l31;
#pragma unroll
                for (int e = 0; e < 16; ++e) {
                    const int r = rbase + (e & 3) + 8 * (e >> 2);
                    ((float*)Cv)[zC + (long long)r * N + c] = -1e30f;
                }
            }
        }
        return;
    }

    const int KD16 = K >> 4;

    const long long aoff0 = ((long long)((brow >> 5) + wr * 2 + 0) * KD16) * 512 + lane * 8;
    const long long aoff1 = aoff0 + (long long)KD16 * 512;
    const long long boff0 = ((long long)((bcol >> 5) + wc * 2 + 0) * KD16) * 512 + lane * 8;
    const long long boff1 = boff0 + (long long)KD16 * 512;

    const unsigned short* __restrict__ pAh0 = Ah + aoff0;
    const unsigned short* __restrict__ pAh1 = Ah + aoff1;
    const unsigned short* __restrict__ pAl0 = Al + aoff0;
    const unsigned short* __restrict__ pAl1 = Al + aoff1;
    const unsigned short* __restrict__ pBh0 = Bh + boff0;
    const unsigned short* __restrict__ pBh1 = Bh + boff1;
    const unsigned short* __restrict__ pBl0 = Bl + boff0;
    const unsigned short* __restrict__ pBl1 = Bl + boff1;

    f32x16 acc00, acc01, acc10, acc11;
#pragma unroll
    for (int e = 0; e < 16; ++e) { acc00[e] = 0.f; acc01[e] = 0.f; acc10[e] = 0.f; acc11[e] = 0.f; }

    bh8 p_ah0, p_ah1, p_al0, p_al1, p_bh0, p_bh1, p_bl0, p_bl1;
    bh8 q_ah0, q_ah1, q_al0, q_al1, q_bh0, q_bh1, q_bl0, q_bl1;

#define MFMA_(d, a, b) d = __builtin_amdgcn_mfma_f32_32x32x16_bf16(a, b, d, 0, 0, 0)

#define LOADSET(S, J) { \
    const long long o_ = (long long)(J) * 512; \
    S##ah0 = *reinterpret_cast<const bh8*>(pAh0 + o_); \
    S##ah1 = *reinterpret_cast<const bh8*>(pAh1 + o_); \
    S##al0 = *reinterpret_cast<const bh8*>(pAl0 + o_); \
    S##al1 = *reinterpret_cast<const bh8*>(pAl1 + o_); \
    S##bh0 = *reinterpret_cast<const bh8*>(pBh0 + o_); \
    S##bh1 = *reinterpret_cast<const bh8*>(pBh1 + o_); \
    S##bl0 = *reinterpret_cast<const bh8*>(pBl0 + o_); \
    S##bl1 = *reinterpret_cast<const bh8*>(pBl1 + o_); }

#define COMPSET(S) { \
    MFMA_(acc00, S##ah0, S##bh0); MFMA_(acc01, S##ah0, S##bh1); \
    MFMA_(acc10, S##ah1, S##bh0); MFMA_(acc11, S##ah1, S##bh1); \
    MFMA_(acc00, S##ah0, S##bl0); MFMA_(acc01, S##ah0, S##bl1); \
    MFMA_(acc10, S##ah1, S##bl0); MFMA_(acc11, S##ah1, S##bl1); \
    MFMA_(acc00, S##al0, S##bh0); MFMA_(acc01, S##al0, S##bh1); \
    MFMA_(acc10, S##al1, S##bh0); MFMA_(acc11, S##al1, S##bh1); }

    LOADSET(p_, 0);
    LOADSET(q_, 1);

    for (int j = 0; j + 3 < KD16; j += 2) {
        if ((j & 7) == 6) __builtin_amdgcn_s_barrier();   // pacing only (no LDS deps)
        __builtin_amdgcn_s_setprio(1);
        COMPSET(p_);
        __builtin_amdgcn_s_setprio(0);
        LOADSET(p_, j + 2);
        __builtin_amdgcn_s_setprio(1);
        COMPSET(q_);
        __builtin_amdgcn_s_setprio(0);
        LOADSET(q_, j + 3);
    }
    COMPSET(p_);
    COMPSET(q_);

#undef LOADSET
#undef COMPSET
#undef MFMA_

    const f32x16* accp[4] = {&acc00, &acc01, &acc10, &acc11};

    // epilogue: C/D 32x32: col = lane&31, row = (e&3)+8*(e>>2)+4*(lane>>5)
#pragma unroll
    for (int mi = 0; mi < 2; ++mi) {
        const int rbase = brow + wr * 64 + mi * 32 + 4 * lhi;
#pragma unroll
        for (int ni = 0; ni < 2; ++ni) {
            const f32x16& a = *accp[mi * 2 + ni];
            const int c = bcol + wc * 64 + ni * 32 + l31;
            float bv = 0.f;
            if (BIAS) {
                const long long bo = biasBase + c;
                bv = bfBias ? bf2f(((const unsigned short*)biasv)[bo])
                            : ((const float*)biasv)[bo];
            }
            if constexpr (OM == 3) {
                // v -> transposed F-layout: (n=c, k=token), per batch z = row>>11
#pragma unroll
                for (int g = 0; g < 4; ++g) {
                    const int t0 = rbase + 8 * g;
                    const int z = t0 >> 11, tt = t0 & 2047;
                    float vv[4];
#pragma unroll
                    for (int d = 0; d < 4; ++d) {
                        float v = a[g * 4 + d];
                        if (BIAS) v += bv;
                        if (RELU) v = fmaxf(v, 0.f);
                        vv[d] = v;
                    }
                    unsigned short h0, l0, h1, l1, h2, l2, h3, l3;
                    splitf(vv[0], h0, l0); splitf(vv[1], h1, l1);
                    splitf(vv[2], h2, l2); splitf(vv[3], h3, l3);
                    const long long o = (long long)z * zOut +
                        (((long long)(c >> 5) * oKD16 + (tt >> 4)) * 2 + ((tt >> 3) & 1)) * 256 +
                        (c & 31) * 8 + (tt & 7);
                    *reinterpret_cast<ushort4*>((unsigned short*)Cv + o) = make_ushort4(h0, h1, h2, h3);
                    *reinterpret_cast<ushort4*>((unsigned short*)Cv2 + o) = make_ushort4(l0, l1, l2, l3);
                }
            } else if constexpr (OM == 1) {
#pragma unroll
                for (int e = 0; e < 16; ++e) {
                    const int r = rbase + (e & 3) + 8 * (e >> 2);
                    float v = a[e];
                    if (BIAS) v += bv;
                    if (RELU) v = fmaxf(v, 0.f);
                    unsigned short hh, ll;
                    splitf(v, hh, ll);
                    const int gr = rowOff + r;
                    const long long o =
                        (((long long)(gr >> 5) * oKD16 + (c >> 4)) * 2 + ((c >> 3) & 1)) * 256 +
                        (gr & 31) * 8 + (c & 7);
                    ((unsigned short*)Cv)[o] = hh;
                    ((unsigned short*)Cv2)[o] = ll;
                }
            } else {
#pragma unroll
                for (int e = 0; e < 16; ++e) {
                    const int r = rbase + (e & 3) + 8 * (e >> 2);
                    float v = a[e];
                    if (BIAS) v += bv;
                    if (MASK) v = (c >= r) ? v * scale : -1e30f;
                    if (RELU) v = fmaxf(v, 0.f);
                    const long long off = zC + (long long)r * N + c;
                    if (bfC) ((__hip_bfloat16*)Cv)[off] = __float2bfloat16(v);
                    else     ((float*)Cv)[off] = v;
                }
            }
        }
    }
}

// softmax over f32 scores row -> split F-layout (K=2048, KD16=128) per batch
__global__ __launch_bounds__(256)
void softmax_k(const float* __restrict__ Sc, unsigned short* __restrict__ Wh,
               unsigned short* __restrict__ Wl) {
    const int m = blockIdx.x, z = blockIdx.y;
    const float* row = Sc + ((long long)z * SEQ + m) * SEQ;
    const int tid = threadIdx.x;

    float v[8];
    float mx = -1e30f;
#pragma unroll
    for (int i = 0; i < 8; ++i) { v[i] = row[tid + i * 256]; mx = fmaxf(mx, v[i]); }
#pragma unroll
    for (int off = 32; off > 0; off >>= 1) mx = fmaxf(mx, __shfl_down(mx, off));

    __shared__ float sm[4];
    __shared__ float ss[4];
    const int wid = tid >> 6, lane = tid & 63;
    if (lane == 0) sm[wid] = mx;
    __syncthreads();
    const float mAll = fmaxf(fmaxf(sm[0], sm[1]), fmaxf(sm[2], sm[3]));

    float s = 0.f;
#pragma unroll
    for (int i = 0; i < 8; ++i) { v[i] = __expf(v[i] - mAll); s += v[i]; }
#pragma unroll
    for (int off = 32; off > 0; off >>= 1) s += __shfl_down(s, off);
    if (lane == 0) ss[wid] = s;
    __syncthreads();
    const float inv = 1.f / (ss[0] + ss[1] + ss[2] + ss[3]);

    unsigned short* wh = Wh + (long long)z * 4194304LL;
    unsigned short* wl = Wl + (long long)z * 4194304LL;
#pragma unroll
    for (int i = 0; i < 8; ++i) {
        const int k = tid + i * 256;
        unsigned short hh, ll;
        splitf(v[i] * inv, hh, ll);
        const long long o = (((long long)(m >> 5) * 128 + (k >> 4)) * 2 + ((k >> 3) & 1)) * 256 +
                            (m & 31) * 8 + (k & 7);
        wh[o] = hh; wl[o] = ll;
    }
}

extern "C" void kernel_launch(void* const* d_in, const int* in_sizes, int n_in,
                              void* d_out, int out_size, void* d_ws, size_t ws_size,
                              hipStream_t stream) {
    const int*  x   = (const int*)d_in[0];
    const void* emb = d_in[1];
    const void* Wq  = d_in[2];
    const void* bq  = d_in[3];
    const void* Wk  = d_in[4];
    const void* bk  = d_in[5];
    const void* Wv  = d_in[6];
    const void* bv  = d_in[7];
    const void* W1  = d_in[8];
    const void* b1  = d_in[9];
    const void* W2  = d_in[10];
    const void* b2  = d_in[11];

    char* ws = (char*)d_ws;
    const long long SZ = 33554432LL;       // 32MB slots; total 7*SZ + 4
    const long long HM = 8388608LL;        // 8M shorts = 16MB
    // slot0: hA(h,l) -> watt_h -> mid_h[lo]     slot4: sc[hi] -> mid_l[hi]
    // slot1: q(h,l)  -> watt_l -> mid_h[hi]     slot5: sc... -> pong(h,l)
    // slot2: kx(h,l) -> att(h,l) (ping)         slot6: wqkv -> wmlp
    // slot3: vxs(h,l) -> mid_l[lo]              7*SZ: flag
    unsigned short* hA_h  = (unsigned short*)(ws);
    unsigned short* hA_l  = hA_h + HM;
    unsigned short* q_h   = (unsigned short*)(ws + SZ);
    unsigned short* q_l   = q_h + HM;
    unsigned short* kx_h  = (unsigned short*)(ws + 2 * SZ);
    unsigned short* kx_l  = kx_h + HM;
    unsigned short* vxs_h = (unsigned short*)(ws + 3 * SZ);
    unsigned short* vxs_l = vxs_h + HM;
    float*          sc    = (float*)(ws + 4 * SZ);
    unsigned short* watt_h = (unsigned short*)(ws);
    unsigned short* watt_l = (unsigned short*)(ws + SZ);
    unsigned short* att_h = (unsigned short*)(ws + 2 * SZ);
    unsigned short* att_l = att_h + HM;
    unsigned short* mid_h = (unsigned short*)(ws);             // 64MB (slots 0-1)
    unsigned short* mid_l = (unsigned short*)(ws + 3 * SZ);    // 64MB (slots 3-4)
    unsigned short* pong_h = (unsigned short*)(ws + 5 * SZ);
    unsigned short* pong_l = pong_h + HM;
    unsigned short* wq_h = (unsigned short*)(ws + 6 * SZ);
    unsigned short* wq_l = wq_h + 1048576;
    unsigned short* wk_h = wq_h + 2097152, * wk_l = wq_h + 3145728;
    unsigned short* wv_h = wq_h + 4194304, * wv_l = wq_h + 5242880;
    unsigned short* w1_h = (unsigned short*)(ws + 6 * SZ);
    unsigned short* w1_l = w1_h + 4194304;
    unsigned short* w2_h = w1_h + 8388608, * w2_l = w1_h + 12582912;
    int* flag = (int*)(ws + 7 * SZ);

    const dim3 b256(256);
    const long long SS = (long long)SEQ * SEQ;
    const long long TSE = 2097152LL;       // 2048*1024 elems

    sniff_k<<<1, 64, 0, stream>>>((const unsigned int*)emb, flag);
    gather_k<<<ROWS, b256, 0, stream>>>(x, emb, hA_h, hA_l, flag);

    splitT_tiled_k<<<dim3(32, 32, 1), b256, 0, stream>>>(Wq, wq_h, wq_l, EDIM, EDIM, 0, flag, 1);
    splitT_tiled_k<<<dim3(32, 32, 1), b256, 0, stream>>>(Wk, wk_h, wk_l, EDIM, EDIM, 0, flag, 1);
    splitT_tiled_k<<<dim3(32, 32, 1), b256, 0, stream>>>(Wv, wv_h, wv_l, EDIM, EDIM, 0, flag, 1);

    // q, k -> F-layout (KD16=64); v -> transposed F-layout (oKD16=128)
    mgemm_k<1, true, false, false><<<dim3(8, 64, 1), b256, 0, stream>>>(
        hA_h, hA_l, wq_h, wq_l, bq, q_h, q_l, ROWS, EDIM, EDIM,
        0, 0, 0, 0, 1.f, 64, 0, 0, flag, 1, 0);
    mgemm_k<1, true, false, false><<<dim3(8, 64, 1), b256, 0, stream>>>(
        hA_h, hA_l, wk_h, wk_l, bk, kx_h, kx_l, ROWS, EDIM, EDIM,
        0, 0, 0, 0, 1.f, 64, 0, 0, flag, 1, 0);
    mgemm_k<3, true, false, false><<<dim3(8, 64, 1), b256, 0, stream>>>(
        hA_h, hA_l, wv_h, wv_l, bv, vxs_h, vxs_l, ROWS, EDIM, EDIM,
        0, 0, 0, 0, 1.f, 128, TSE, 0, flag, 1, 0);

    // scores = (q @ k^T) * scale, suffix mask -> f32
    mgemm_k<0, false, false, true><<<dim3(16, 16, NB), b256, 0, stream>>>(
        q_h, q_l, kx_h, kx_l, nullptr, sc, nullptr, SEQ, SEQ, EDIM,
        TSE, TSE, SS, 0, 0.03125f, 0, 0, 0, flag, 0, 0);

    softmax_k<<<dim3(SEQ, NB), b256, 0, stream>>>(sc, watt_h, watt_l);

    // att = relu(w @ v) -> F-layout (global rows z*2048+r)
    mgemm_k<1, false, true, false><<<dim3(8, 16, NB), b256, 0, stream>>>(
        watt_h, watt_l, vxs_h, vxs_l, nullptr, att_h, att_l, SEQ, EDIM, SEQ,
        4194304LL, TSE, 0, 0, 1.f, 64, 0, 2048, flag, 0, 0);

    // MLP
    const unsigned short* cur_h = att_h;
    const unsigned short* cur_l = att_l;
    for (int i = 0; i < 4; ++i) {
        splitT_tiled_k<<<dim3(128, 32, 1), b256, 0, stream>>>(
            W1, w1_h, w1_l, EDIM, MDIM, (long long)i * EDIM * MDIM, flag, 1);
        mgemm_k<1, true, true, false><<<dim3(32, 64, 1), b256, 0, stream>>>(
            cur_h, cur_l, w1_h, w1_l, b1, mid_h, mid_l, ROWS, MDIM, EDIM,
            0, 0, 0, (long long)i * MDIM, 1.f, 256, 0, 0, flag, 1, 0);

        splitT_tiled_k<<<dim3(32, 128, 1), b256, 0, stream>>>(
            W2, w2_h, w2_l, MDIM, EDIM, (long long)i * MDIM * EDIM, flag, 1);
        if (i < 3) {
            unsigned short* oh = (cur_h == att_h) ? pong_h : att_h;
            unsigned short* ol = (cur_h == att_h) ? pong_l : att_l;
            mgemm_k<1, true, true, false><<<dim3(8, 64, 1), b256, 0, stream>>>(
                mid_h, mid_l, w2_h, w2_l, b2, oh, ol, ROWS, EDIM, MDIM,
                0, 0, 0, (long long)i * EDIM, 1.f, 64, 0, 0, flag, 1, 0);
            cur_h = oh; cur_l = ol;
        } else {
            mgemm_k<0, true, true, false><<<dim3(8, 64, 1), b256, 0, stream>>>(
                mid_h, mid_l, w2_h, w2_l, b2, d_out, nullptr, ROWS, EDIM, MDIM,
                0, 0, 0, (long long)i * EDIM, 1.f, 0, 0, 0, flag, 1, 1);
        }
    }
}

// Round 5
// 2199.429 us; speedup vs baseline: 1.1775x; 1.1775x over previous
//
#include <hip/hip_runtime.h>
#include <hip/hip_bf16.h>

#define EDIM 1024
#define MDIM 4096
#define SEQ  2048
#define NB   4
#define ROWS 8192

typedef short bh8 __attribute__((ext_vector_type(8)));
typedef float f32x16 __attribute__((ext_vector_type(16)));

__device__ __forceinline__ float bf2f(unsigned short u) {
    return __uint_as_float(((unsigned int)u) << 16);
}
__device__ __forceinline__ unsigned short f2bf(float f) {
    unsigned int u = __float_as_uint(f);
    u += 0x7FFFu + ((u >> 16) & 1u);
    return (unsigned short)(u >> 16);
}
__device__ __forceinline__ void splitf(float v, unsigned short& h, unsigned short& l) {
    h = f2bf(v);
    l = f2bf(v - __uint_as_float(((unsigned int)h) << 16));
}
__device__ __forceinline__ void ld4f(const float* __restrict__ p, float* d) {
    const float4 v = *reinterpret_cast<const float4*>(p);
    d[0] = v.x; d[1] = v.y; d[2] = v.z; d[3] = v.w;
}
__device__ __forceinline__ void ld4h(const unsigned short* __restrict__ p, float* d) {
    const ushort4 v = *reinterpret_cast<const ushort4*>(p);
    d[0] = bf2f(v.x); d[1] = bf2f(v.y); d[2] = bf2f(v.z); d[3] = bf2f(v.w);
}

// async global->LDS, 16B per lane; dest = wave-uniform base + lane*16
__device__ __forceinline__ void async_copy16(void* lds, const void* g) {
    __builtin_amdgcn_global_load_lds(
        (const __attribute__((address_space(1))) unsigned int*)g,
        (__attribute__((address_space(3))) unsigned int*)lds, 16, 0, 0);
}

// F-layout index: element (n,k) of an [N][K] matrix lives at
// ((((n/32)*(K/16)+k/16)*2+(k/8)%2)*32 + n%32)*8 (+ k%8).
// One (n32-group, k16) = 1KB contiguous = exactly one MFMA operand image.
__device__ __forceinline__ long long tidx8(int n, int k, int KD16) {
    return ((((long long)(n >> 5) * KD16 + (k >> 4)) * 2 + ((k >> 3) & 1)) * 32 + (n & 31)) * 8;
}

// dtype sniffer: flag=1 -> inputs are bf16, flag=0 -> f32
__global__ __launch_bounds__(64)
void sniff_k(const unsigned int* __restrict__ w, int* __restrict__ flag) {
    int ok = 0;
    const int base = threadIdx.x * 32;
#pragma unroll
    for (int i = 0; i < 32; ++i) {
        const unsigned int v = w[base + i];
        const unsigned int lo = v & 0xFFFFu, hi = v >> 16;
        const unsigned int el = (lo >> 7) & 0xFF, eh = (hi >> 7) & 0xFF;
        const bool okl = (lo == 0u) || (el >= 0x30u && el <= 0x7Eu);
        const bool okh = (hi == 0u) || (eh >= 0x30u && eh <= 0x7Eu);
        ok += (okl && okh) ? 1 : 0;
    }
#pragma unroll
    for (int off = 32; off > 0; off >>= 1) ok += __shfl_down(ok, off);
    if (threadIdx.x == 0) *flag = (ok > 1400) ? 1 : 0;
}

// embedding gather -> h in split F-layout (KD16=64)
__global__ __launch_bounds__(256)
void gather_k(const int* __restrict__ x, const void* __restrict__ emb,
              unsigned short* __restrict__ oh, unsigned short* __restrict__ ol,
              const int* __restrict__ flagp) {
    const int bf = *flagp;
    const int row = blockIdx.x;
    const int idx = x[row];
    const int k = threadIdx.x * 4;
    const long long off = (long long)idx * EDIM + k;
    float d[4];
    if (bf) ld4h((const unsigned short*)emb + off, d);
    else    ld4f((const float*)emb + off, d);
    unsigned short h0, l0, h1, l1, h2, l2, h3, l3;
    splitf(d[0], h0, l0); splitf(d[1], h1, l1);
    splitf(d[2], h2, l2); splitf(d[3], h3, l3);
    const long long o = (((long long)(row >> 5) * 64 + (k >> 4)) * 2 + ((k >> 3) & 1)) * 256
                        + (row & 31) * 8 + (k & 7);
    *reinterpret_cast<ushort4*>(oh + o) = make_ushort4(h0, h1, h2, h3);
    *reinterpret_cast<ushort4*>(ol + o) = make_ushort4(l0, l1, l2, l3);
}

// Weights: transpose + split + fragment-tile: in [Kd,Nd] -> hi/lo tiled [Nd,Kd]
__global__ __launch_bounds__(256)
void splitT_tiled_k(const void* __restrict__ in, unsigned short* __restrict__ oh,
                    unsigned short* __restrict__ ol, int Kd, int Nd,
                    long long inOff, const int* __restrict__ flagp, int bF) {
    const int bf = bF ? *flagp : 0;
    const int k0 = blockIdx.y * 32, n0 = blockIdx.x * 32;
    const int KD16 = Kd >> 4;
    __shared__ float t[32][33];
    const int c = threadIdx.x & 31, r0 = threadIdx.x >> 5;
#pragma unroll
    for (int i = 0; i < 4; ++i) {
        const int r = r0 + i * 8;
        const long long off = inOff + (long long)(k0 + r) * Nd + n0 + c;
        t[r][c] = bf ? bf2f(((const unsigned short*)in)[off]) : ((const float*)in)[off];
    }
    __syncthreads();
#pragma unroll
    for (int i = 0; i < 4; ++i) {
        const int r = r0 + i * 8;
        const float v = t[c][r];
        unsigned short hh, ll;
        splitf(v, hh, ll);
        const int n = n0 + r, k = k0 + c;
        const long long oo = tidx8(n, k, KD16) + (k & 7);
        oh[oo] = hh; ol[oo] = ll;
    }
}

// Split-bf16 MFMA GEMM, both operands staged to LDS via global_load_lds.
// Tile BM x 256, BK=32, 512 threads = 8 waves (2M x 4N), wave tile (BM/2) x 64,
// 32x32x16 MFMA, 3-term hi/lo split. Double-buffered LDS, counted vmcnt
// (never 0 in main loop), raw s_barrier. 1 block/CU.
// OM: 0 = plain C, 1 = F-layout hi/lo out, 3 = transposed F-layout out.
template<int BM, int OM, bool BIAS, bool RELU, bool MASK>
__global__ __launch_bounds__(512, 2)
void mgemm_k(const unsigned short* __restrict__ Ah,
             const unsigned short* __restrict__ Al,
             const unsigned short* __restrict__ Bh,
             const unsigned short* __restrict__ Bl,
             const void* __restrict__ biasv,
             void* __restrict__ Cv, void* __restrict__ Cv2,
             int M, int N, int K,
             long long sA, long long sB, long long sC,
             long long biasBase, float scale, int oKD16, long long zOut, int rowMul,
             const int* __restrict__ flagp, int bF, int cF) {
    constexpr int MF = BM / 64;          // M frags per wave (4 or 2)
    constexpr int NA = BM / 8;           // A frags per K-step
    constexpr int NR = (NA + 32) / 8;    // stage issues per wave per K-step (8 or 6)
    constexpr int ABYTES = BM * 128;     // A bytes per buffer
    constexpr int BUFB = ABYTES + 32768; // + B bytes

    const int flag = *flagp;
    const int bfBias = bF ? flag : 0;
    const int bfC = cF ? flag : 0;

    Ah += (long long)blockIdx.z * sA;
    Al += (long long)blockIdx.z * sA;
    Bh += (long long)blockIdx.z * sB;
    Bl += (long long)blockIdx.z * sB;
    const long long zC = (long long)blockIdx.z * sC;
    const int rowOff = rowMul * blockIdx.z;

    // bijective XCD swizzle (nwg per z is a multiple of 8 for all our grids)
    const int GX = gridDim.x;
    const int nwg = GX * gridDim.y;
    const int f = blockIdx.y * GX + blockIdx.x;
    const int idx = (f & 7) * (nwg >> 3) + (f >> 3);
    const int bx = idx % GX, by = idx / GX;
    const int brow = by * BM, bcol = bx * 256;

    const int tid = threadIdx.x;
    const int lane = tid & 63, wave = tid >> 6;
    const int wr = wave >> 2, wc = wave & 3;
    const int l31 = lane & 31, lhi = lane >> 5;

    if (MASK && (bcol + 255 < brow)) {
#pragma unroll
        for (int mi = 0; mi < MF; ++mi) {
            const int rbase = brow + wr * (BM / 2) + mi * 32 + 4 * lhi;
#pragma unroll
            for (int ni = 0; ni < 2; ++ni) {
                const int c = bcol + wc * 64 + ni * 32 + l31;
#pragma unroll
                for (int e = 0; e < 16; ++e) {
                    const int r = rbase + (e & 3) + 8 * (e >> 2);
                    ((float*)Cv)[zC + (long long)r * N + c] = -1e30f;
                }
            }
        }
        return;
    }

    __shared__ __align__(16) char Lds[2][BUFB];

    f32x16 acc[MF][2];
#pragma unroll
    for (int a = 0; a < MF; ++a)
#pragma unroll
        for (int b = 0; b < 2; ++b)
#pragma unroll
            for (int e = 0; e < 16; ++e) acc[a][b][e] = 0.f;

    const int KD16 = K >> 4;

    // per-wave staging descriptors: wave stages frags j = 8r + wave
    const unsigned short* sp[NR];
    int dof[NR];
#pragma unroll
    for (int r = 0; r < NR; ++r) {
        const int j = r * 8 + wave;
        if (j < NA) {
            const int g = j >> 2, c01 = (j >> 1) & 1, hh = j & 1;
            sp[r] = (hh ? Al : Ah) +
                    ((long long)((brow >> 5) + g) * KD16 + c01) * 512 + lane * 8;
            dof[r] = j * 1024;
        } else {
            const int jb = j - NA;
            const int g = jb >> 2, c01 = (jb >> 1) & 1, hh = jb & 1;
            sp[r] = (hh ? Bl : Bh) +
                    ((long long)((bcol >> 5) + g) * KD16 + c01) * 512 + lane * 8;
            dof[r] = ABYTES + jb * 1024;
        }
    }

#define STAGE(BUF) { \
    char* lb_ = &Lds[BUF][0]; \
    _Pragma("unroll") \
    for (int r = 0; r < NR; ++r) { async_copy16(lb_ + dof[r], sp[r]); sp[r] += 1024; } }

#define COMPUTE(CUR) { \
    const char* lb_ = &Lds[CUR][0] + lane * 16; \
    _Pragma("unroll") \
    for (int c = 0; c < 2; ++c) { \
        bh8 aH[MF], aL[MF], bH[2], bL[2]; \
        _Pragma("unroll") \
        for (int ni = 0; ni < 2; ++ni) { \
            const int jb = ((wc * 2 + ni) * 2 + c) * 2; \
            bH[ni] = *reinterpret_cast<const bh8*>(lb_ + ABYTES + jb * 1024); \
            bL[ni] = *reinterpret_cast<const bh8*>(lb_ + ABYTES + jb * 1024 + 1024); \
        } \
        _Pragma("unroll") \
        for (int mi = 0; mi < MF; ++mi) { \
            const int ja = ((wr * MF + mi) * 2 + c) * 2; \
            aH[mi] = *reinterpret_cast<const bh8*>(lb_ + ja * 1024); \
            aL[mi] = *reinterpret_cast<const bh8*>(lb_ + ja * 1024 + 1024); \
        } \
        __builtin_amdgcn_s_setprio(1); \
        _Pragma("unroll") \
        for (int mi = 0; mi < MF; ++mi) { \
            _Pragma("unroll") \
            for (int ni = 0; ni < 2; ++ni) { \
                acc[mi][ni] = __builtin_amdgcn_mfma_f32_32x32x16_bf16(aH[mi], bH[ni], acc[mi][ni], 0, 0, 0); \
                acc[mi][ni] = __builtin_amdgcn_mfma_f32_32x32x16_bf16(aH[mi], bL[ni], acc[mi][ni], 0, 0, 0); \
                acc[mi][ni] = __builtin_amdgcn_mfma_f32_32x32x16_bf16(aL[mi], bH[ni], acc[mi][ni], 0, 0, 0); \
            } \
        } \
        __builtin_amdgcn_s_setprio(0); \
    } }

    const int NT = K >> 5;

    STAGE(0);
    for (int t = 0; t < NT - 1; ++t) {
        const int cur = t & 1;
        STAGE(cur ^ 1);
        if constexpr (NR == 8) asm volatile("s_waitcnt vmcnt(8)" ::: "memory");
        else                   asm volatile("s_waitcnt vmcnt(6)" ::: "memory");
        __builtin_amdgcn_sched_barrier(0);
        __builtin_amdgcn_s_barrier();
        __builtin_amdgcn_sched_barrier(0);
        COMPUTE(cur);
        __builtin_amdgcn_sched_barrier(0);
        __builtin_amdgcn_s_barrier();
    }
    asm volatile("s_waitcnt vmcnt(0)" ::: "memory");
    __builtin_amdgcn_sched_barrier(0);
    __builtin_amdgcn_s_barrier();
    __builtin_amdgcn_sched_barrier(0);
    COMPUTE((NT - 1) & 1);

#undef STAGE
#undef COMPUTE

    // epilogue: C/D 32x32: col = lane&31, row = (e&3)+8*(e>>2)+4*(lane>>5)
#pragma unroll
    for (int mi = 0; mi < MF; ++mi) {
        const int rbase = brow + wr * (BM / 2) + mi * 32 + 4 * lhi;
#pragma unroll
        for (int ni = 0; ni < 2; ++ni) {
            const f32x16& a = acc[mi][ni];
            const int c = bcol + wc * 64 + ni * 32 + l31;
            float bv = 0.f;
            if (BIAS) {
                const long long bo = biasBase + c;
                bv = bfBias ? bf2f(((const unsigned short*)biasv)[bo])
                            : ((const float*)biasv)[bo];
            }
            if constexpr (OM == 3) {
                // transposed F-layout: (n=c, k=token), batch z = row>>11
#pragma unroll
                for (int g = 0; g < 4; ++g) {
                    const int t0 = rbase + 8 * g;
                    const int z = t0 >> 11, tt = t0 & 2047;
                    float vv[4];
#pragma unroll
                    for (int d = 0; d < 4; ++d) {
                        float v = a[g * 4 + d];
                        if (BIAS) v += bv;
                        if (RELU) v = fmaxf(v, 0.f);
                        vv[d] = v;
                    }
                    unsigned short h0, l0, h1, l1, h2, l2, h3, l3;
                    splitf(vv[0], h0, l0); splitf(vv[1], h1, l1);
                    splitf(vv[2], h2, l2); splitf(vv[3], h3, l3);
                    const long long o = (long long)z * zOut +
                        (((long long)(c >> 5) * oKD16 + (tt >> 4)) * 2 + ((tt >> 3) & 1)) * 256 +
                        (c & 31) * 8 + (tt & 7);
                    *reinterpret_cast<ushort4*>((unsigned short*)Cv + o) = make_ushort4(h0, h1, h2, h3);
                    *reinterpret_cast<ushort4*>((unsigned short*)Cv2 + o) = make_ushort4(l0, l1, l2, l3);
                }
            } else if constexpr (OM == 1) {
#pragma unroll
                for (int e = 0; e < 16; ++e) {
                    const int r = rbase + (e & 3) + 8 * (e >> 2);
                    float v = a[e];
                    if (BIAS) v += bv;
                    if (RELU) v = fmaxf(v, 0.f);
                    unsigned short hh, ll;
                    splitf(v, hh, ll);
                    const int gr = rowOff + r;
                    const long long o =
                        (((long long)(gr >> 5) * oKD16 + (c >> 4)) * 2 + ((c >> 3) & 1)) * 256 +
                        (gr & 31) * 8 + (c & 7);
                    ((unsigned short*)Cv)[o] = hh;
                    ((unsigned short*)Cv2)[o] = ll;
                }
            } else {
#pragma unroll
                for (int e = 0; e < 16; ++e) {
                    const int r = rbase + (e & 3) + 8 * (e >> 2);
                    float v = a[e];
                    if (BIAS) v += bv;
                    if (MASK) v = (c >= r) ? v * scale : -1e30f;
                    if (RELU) v = fmaxf(v, 0.f);
                    const long long off = zC + (long long)r * N + c;
                    if (bfC) ((__hip_bfloat16*)Cv)[off] = __float2bfloat16(v);
                    else     ((float*)Cv)[off] = v;
                }
            }
        }
    }
}

// softmax over f32 scores row -> split F-layout (K=2048, KD16=128) per batch
__global__ __launch_bounds__(256)
void softmax_k(const float* __restrict__ Sc, unsigned short* __restrict__ Wh,
               unsigned short* __restrict__ Wl) {
    const int m = blockIdx.x, z = blockIdx.y;
    const float* row = Sc + ((long long)z * SEQ + m) * SEQ;
    const int tid = threadIdx.x;

    float v[8];
    float mx = -1e30f;
#pragma unroll
    for (int i = 0; i < 8; ++i) { v[i] = row[tid + i * 256]; mx = fmaxf(mx, v[i]); }
#pragma unroll
    for (int off = 32; off > 0; off >>= 1) mx = fmaxf(mx, __shfl_down(mx, off));

    __shared__ float sm[4];
    __shared__ float ss[4];
    const int wid = tid >> 6, lane = tid & 63;
    if (lane == 0) sm[wid] = mx;
    __syncthreads();
    const float mAll = fmaxf(fmaxf(sm[0], sm[1]), fmaxf(sm[2], sm[3]));

    float s = 0.f;
#pragma unroll
    for (int i = 0; i < 8; ++i) { v[i] = __expf(v[i] - mAll); s += v[i]; }
#pragma unroll
    for (int off = 32; off > 0; off >>= 1) s += __shfl_down(s, off);
    if (lane == 0) ss[wid] = s;
    __syncthreads();
    const float inv = 1.f / (ss[0] + ss[1] + ss[2] + ss[3]);

    unsigned short* wh = Wh + (long long)z * 4194304LL;
    unsigned short* wl = Wl + (long long)z * 4194304LL;
#pragma unroll
    for (int i = 0; i < 8; ++i) {
        const int k = tid + i * 256;
        unsigned short hh, ll;
        splitf(v[i] * inv, hh, ll);
        const long long o = (((long long)(m >> 5) * 128 + (k >> 4)) * 2 + ((k >> 3) & 1)) * 256 +
                            (m & 31) * 8 + (k & 7);
        wh[o] = hh; wl[o] = ll;
    }
}

extern "C" void kernel_launch(void* const* d_in, const int* in_sizes, int n_in,
                              void* d_out, int out_size, void* d_ws, size_t ws_size,
                              hipStream_t stream) {
    const int*  x   = (const int*)d_in[0];
    const void* emb = d_in[1];
    const void* Wq  = d_in[2];
    const void* bq  = d_in[3];
    const void* Wk  = d_in[4];
    const void* bk  = d_in[5];
    const void* Wv  = d_in[6];
    const void* bv  = d_in[7];
    const void* W1  = d_in[8];
    const void* b1  = d_in[9];
    const void* W2  = d_in[10];
    const void* b2  = d_in[11];

    char* ws = (char*)d_ws;
    const long long SZ = 33554432LL;       // 32MB slots; total 7*SZ + 4
    const long long HM = 8388608LL;        // 8M shorts = 16MB
    unsigned short* hA_h  = (unsigned short*)(ws);
    unsigned short* hA_l  = hA_h + HM;
    unsigned short* q_h   = (unsigned short*)(ws + SZ);
    unsigned short* q_l   = q_h + HM;
    unsigned short* kx_h  = (unsigned short*)(ws + 2 * SZ);
    unsigned short* kx_l  = kx_h + HM;
    unsigned short* vxs_h = (unsigned short*)(ws + 3 * SZ);
    unsigned short* vxs_l = vxs_h + HM;
    float*          sc    = (float*)(ws + 4 * SZ);
    unsigned short* watt_h = (unsigned short*)(ws);
    unsigned short* watt_l = (unsigned short*)(ws + SZ);
    unsigned short* att_h = (unsigned short*)(ws + 2 * SZ);
    unsigned short* att_l = att_h + HM;
    unsigned short* mid_h = (unsigned short*)(ws);             // slots 0-1
    unsigned short* mid_l = (unsigned short*)(ws + 3 * SZ);    // slots 3-4
    unsigned short* pong_h = (unsigned short*)(ws + 5 * SZ);
    unsigned short* pong_l = pong_h + HM;
    unsigned short* wq_h = (unsigned short*)(ws + 6 * SZ);
    unsigned short* wq_l = wq_h + 1048576;
    unsigned short* wk_h = wq_h + 2097152, * wk_l = wq_h + 3145728;
    unsigned short* wv_h = wq_h + 4194304, * wv_l = wq_h + 5242880;
    unsigned short* w1_h = (unsigned short*)(ws + 6 * SZ);
    unsigned short* w1_l = w1_h + 4194304;
    unsigned short* w2_h = w1_h + 8388608, * w2_l = w1_h + 12582912;
    int* flag = (int*)(ws + 7 * SZ);

    const dim3 b256(256), b512(512);
    const long long SS = (long long)SEQ * SEQ;
    const long long TSE = 2097152LL;       // 2048*1024 elems

    sniff_k<<<1, 64, 0, stream>>>((const unsigned int*)emb, flag);
    gather_k<<<ROWS, b256, 0, stream>>>(x, emb, hA_h, hA_l, flag);

    splitT_tiled_k<<<dim3(32, 32, 1), b256, 0, stream>>>(Wq, wq_h, wq_l, EDIM, EDIM, 0, flag, 1);
    splitT_tiled_k<<<dim3(32, 32, 1), b256, 0, stream>>>(Wk, wk_h, wk_l, EDIM, EDIM, 0, flag, 1);
    splitT_tiled_k<<<dim3(32, 32, 1), b256, 0, stream>>>(Wv, wv_h, wv_l, EDIM, EDIM, 0, flag, 1);

    // q, k -> F-layout (oKD16=64); v -> transposed F-layout (oKD16=128)
    mgemm_k<128, 1, true, false, false><<<dim3(4, 64, 1), b512, 0, stream>>>(
        hA_h, hA_l, wq_h, wq_l, bq, q_h, q_l, ROWS, EDIM, EDIM,
        0, 0, 0, 0, 1.f, 64, 0, 0, flag, 1, 0);
    mgemm_k<128, 1, true, false, false><<<dim3(4, 64, 1), b512, 0, stream>>>(
        hA_h, hA_l, wk_h, wk_l, bk, kx_h, kx_l, ROWS, EDIM, EDIM,
        0, 0, 0, 0, 1.f, 64, 0, 0, flag, 1, 0);
    mgemm_k<128, 3, true, false, false><<<dim3(4, 64, 1), b512, 0, stream>>>(
        hA_h, hA_l, wv_h, wv_l, bv, vxs_h, vxs_l, ROWS, EDIM, EDIM,
        0, 0, 0, 0, 1.f, 128, TSE, 0, flag, 1, 0);

    // scores = (q @ k^T) * scale, suffix mask -> f32
    mgemm_k<256, 0, false, false, true><<<dim3(8, 8, NB), b512, 0, stream>>>(
        q_h, q_l, kx_h, kx_l, nullptr, sc, nullptr, SEQ, SEQ, EDIM,
        TSE, TSE, SS, 0, 0.03125f, 0, 0, 0, flag, 0, 0);

    softmax_k<<<dim3(SEQ, NB), b256, 0, stream>>>(sc, watt_h, watt_l);

    // att = relu(w @ v) -> F-layout (global rows z*2048+r)
    mgemm_k<128, 1, false, true, false><<<dim3(4, 16, NB), b512, 0, stream>>>(
        watt_h, watt_l, vxs_h, vxs_l, nullptr, att_h, att_l, SEQ, EDIM, SEQ,
        4194304LL, TSE, 0, 0, 1.f, 64, 0, 2048, flag, 0, 0);

    // MLP
    const unsigned short* cur_h = att_h;
    const unsigned short* cur_l = att_l;
    for (int i = 0; i < 4; ++i) {
        splitT_tiled_k<<<dim3(128, 32, 1), b256, 0, stream>>>(
            W1, w1_h, w1_l, EDIM, MDIM, (long long)i * EDIM * MDIM, flag, 1);
        mgemm_k<256, 1, true, true, false><<<dim3(16, 32, 1), b512, 0, stream>>>(
            cur_h, cur_l, w1_h, w1_l, b1, mid_h, mid_l, ROWS, MDIM, EDIM,
            0, 0, 0, (long long)i * MDIM, 1.f, 256, 0, 0, flag, 1, 0);

        splitT_tiled_k<<<dim3(32, 128, 1), b256, 0, stream>>>(
            W2, w2_h, w2_l, MDIM, EDIM, (long long)i * MDIM * EDIM, flag, 1);
        if (i < 3) {
            unsigned short* oh = (cur_h == att_h) ? pong_h : att_h;
            unsigned short* ol = (cur_h == att_h) ? pong_l : att_l;
            mgemm_k<128, 1, true, true, false><<<dim3(4, 64, 1), b512, 0, stream>>>(
                mid_h, mid_l, w2_h, w2_l, b2, oh, ol, ROWS, EDIM, MDIM,
                0, 0, 0, (long long)i * EDIM, 1.f, 64, 0, 0, flag, 1, 0);
            cur_h = oh; cur_l = ol;
        } else {
            mgemm_k<128, 0, true, true, false><<<dim3(4, 64, 1), b512, 0, stream>>>(
                mid_h, mid_l, w2_h, w2_l, b2, d_out, nullptr, ROWS, EDIM, MDIM,
                0, 0, 0, (long long)i * EDIM, 1.f, 0, 0, 0, flag, 1, 1);
        }
    }
}